// Round 4
// baseline (441.201 us; speedup 1.0000x reference)
//
#include <hip/hip_runtime.h>
#include <math.h>

// NerfactoModel fused forward, MFMA r4: software-pipelined across tiles.
// Per wave: 64 samples/tile. Acts in per-wave LDS [64 x 72 bf16, stride 144B].
// Iter i: write staged enc -> issue tile i+1 loads -> dens chain -> app gather
// (staged cam) + staged edir write -> col chain -> compute tile i+1 enc/dir
// into regs. Input latency + enc/dir VALU hide under the MFMA/LDS chain.

typedef short short8 __attribute__((ext_vector_type(8)));
typedef float f32x4 __attribute__((ext_vector_type(4)));
typedef float f32x4a __attribute__((ext_vector_type(4), aligned(4)));
typedef float f32x2a __attribute__((ext_vector_type(2), aligned(4)));
typedef unsigned int uint;
typedef unsigned short ushort;

struct EncC { float rf[16]; };   // (RES[l]-1) as float

#define PY 2481   // 2654435761 % 4096
#define PZ 1941   // 805459861 % 4096

#define MFMA(A,B,C) __builtin_amdgcn_mfma_f32_16x16x32_bf16(A, B, C, 0, 0, 0)

// ---- LDS layout (bytes) ----
#define W1_OFF   0        // dens_w1^T  64 x 40 bf16 (5120)
#define W3_OFF   5120     // dens_w3^T  16 x 72 bf16 (2304)
#define C3_OFF   7424     // col_w3^T   16 x 72 bf16 (2304)
#define DB1_OFF  9728     // f32 biases
#define DB2_OFF  9984
#define DB3_OFF  10240
#define CB1_OFF  10304
#define CB2_OFF  10560
#define CB3_OFF  10816
// staging-only region (freed after A-frag preload), reused by ACT:
#define W2_OFF   10848    // dens_w2^T  64 x 72 (9216)
#define C1_OFF   20064    // col_w1^T (permuted K) 64 x 72 (9216)
#define C2_OFF   29280    // col_w2^T   64 x 72 (9216)
#define ACT_OFF  10848    // 4 waves x 64 rows x 144 B = 36864
#define LDS_BYTES 47712

__device__ __forceinline__ uint bf16rne(float x) {
    uint u = __builtin_bit_cast(uint, x);
    return (u + 0x7fffu + ((u >> 16) & 1u)) >> 16;
}
// truncation pack: one v_perm_b32
__device__ __forceinline__ uint pktr(float lo, float hi) {
    return __builtin_amdgcn_perm(__builtin_bit_cast(uint, hi),
                                 __builtin_bit_cast(uint, lo), 0x07060302u);
}

// writeback: relu + bf16 trunc-pack, in place (bias already in acc).
__device__ __forceinline__ void layer_wb(const f32x4* acc, char* rowp, int q) {
#pragma unroll
    for (int mt = 0; mt < 4; ++mt) {
        const f32x4 v = acc[mt];
        uint2 pw;
        pw.x = pktr(fmaxf(v[0], 0.f), fmaxf(v[1], 0.f));
        pw.y = pktr(fmaxf(v[2], 0.f), fmaxf(v[3], 0.f));
        *(uint2*)(rowp + mt*32 + q*8) = pw;
    }
}

// full 64->64 layer (K=64), A-frags persistent in registers, bias as C-init.
__device__ __forceinline__ void layer64(char* wact, const short8* aw,
                                        const char* biasp, int l15, int q) {
    const int q16 = q * 16;
    f32x4 bf[4];
#pragma unroll
    for (int mt = 0; mt < 4; ++mt)
        bf[mt] = *(const f32x4*)(biasp + mt*64 + q16);
#pragma unroll
    for (int nt = 0; nt < 4; ++nt) {
        char* rowp = wact + (nt*16 + l15)*144;
        short8 b0 = *(const short8*)(rowp + q16);
        short8 b1 = *(const short8*)(rowp + 64 + q16);
        f32x4 acc[4];
#pragma unroll
        for (int mt = 0; mt < 4; ++mt) {
            f32x4 z = MFMA(aw[2*mt], b0, bf[mt]);
            acc[mt] = MFMA(aw[2*mt + 1], b1, z);
        }
        layer_wb(acc, rowp, q);
    }
}

// compute enc hash packs + dir-MLP packs for a sample from preloaded inputs
__device__ __forceinline__ void stage_inputs(
    float rx, float ry, float rz, float dx, float dy, float dz,
    float a0x, float a0y, float a0z, float ivx, float ivy, float ivz,
    const float* __restrict__ ht,
    const float* __restrict__ dir_w1, const float* __restrict__ dir_b1,
    const float* __restrict__ dir_w2, const float* __restrict__ dir_b2,
    const EncC& enc, uint* encp, uint* ep)
{
    const float px = fminf(fmaxf((rx - a0x)*ivx, 0.f), 1.f);
    const float py = fminf(fmaxf((ry - a0y)*ivy, 0.f), 1.f);
    const float pz = fminf(fmaxf((rz - a0z)*ivz, 0.f), 1.f);
#pragma unroll
    for (int l = 0; l < 16; ++l) {
        const float rf = enc.rf[l];
        const int cx = (int)(px*rf), cy = (int)(py*rf), cz = (int)(pz*rf);
        const int h = (cx + cy*PY + cz*PZ) & 4095;
        const float2 f = *(const float2*)(ht + (((l<<12) + h) << 1));
        encp[l] = pktr(f.x, f.y);
    }
    float e1[16];
#pragma unroll
    for (int j = 0; j < 16; ++j)
        e1[j] = fmaxf(fmaf(dx, dir_w1[j],
                      fmaf(dy, dir_w1[16+j],
                      fmaf(dz, dir_w1[32+j], dir_b1[j]))), 0.f);
    float ed[16];
#pragma unroll
    for (int j = 0; j < 16; ++j) ed[j] = dir_b2[j];
#pragma unroll
    for (int i = 0; i < 16; ++i) {
        const float e = e1[i];
#pragma unroll
        for (int j = 0; j < 16; ++j) ed[j] = fmaf(e, dir_w2[i*16+j], ed[j]);
    }
#pragma unroll
    for (int j = 0; j < 8; ++j) ep[j] = pktr(ed[2*j], ed[2*j+1]);
}

__global__ __launch_bounds__(256, 3)
void nerf_mfma(const float* __restrict__ ray, const float* __restrict__ dirs,
               const int* __restrict__ cam_idx, const float* __restrict__ aabb,
               const float* __restrict__ ht,
               const float* __restrict__ dir_w1, const float* __restrict__ dir_b1,
               const float* __restrict__ dir_w2, const float* __restrict__ dir_b2,
               const float* __restrict__ dens_w1, const float* __restrict__ dens_b1,
               const float* __restrict__ dens_w2, const float* __restrict__ dens_b2,
               const float* __restrict__ dens_w3, const float* __restrict__ dens_b3,
               const float* __restrict__ col_w1, const float* __restrict__ col_b1,
               const float* __restrict__ col_w2, const float* __restrict__ col_b2,
               const float* __restrict__ col_w3, const float* __restrict__ col_b3,
               const float* __restrict__ app_emb,
               float* __restrict__ out, int n, EncC enc)
{
    __shared__ __align__(16) char smem[LDS_BYTES];
    const int t = threadIdx.x;

    // ---- zero weight staging area (pad slots must read as 0) ----
    {
        uint* z = (uint*)smem;
        for (int i = t; i < 38496/4; i += 256) z[i] = 0;
    }
    __syncthreads();
    // ---- stage weights: bf16 (RNE, once per block), transposed [out][in] ----
    {
        ushort* w1t = (ushort*)(smem + W1_OFF);
        for (int e = t; e < 2048; e += 256) w1t[(e&63)*40 + (e>>6)] = (ushort)bf16rne(dens_w1[e]);
        ushort* w2t = (ushort*)(smem + W2_OFF);
        for (int e = t; e < 4096; e += 256) w2t[(e&63)*72 + (e>>6)] = (ushort)bf16rne(dens_w2[e]);
        ushort* w3t = (ushort*)(smem + W3_OFF);
        for (int e = t; e < 1024; e += 256) w3t[(e&15)*72 + (e>>4)] = (ushort)bf16rne(dens_w3[e]);
        ushort* c1t = (ushort*)(smem + C1_OFF);
        for (int e = t; e < 4032; e += 256) {
            int in = e >> 6, o = e & 63;
            int pk = (in < 15) ? (in + 49) : ((in < 31) ? (in + 17) : (in - 31));
            c1t[o*72 + pk] = (ushort)bf16rne(col_w1[e]);
        }
        ushort* c2t = (ushort*)(smem + C2_OFF);
        for (int e = t; e < 4096; e += 256) c2t[(e&63)*72 + (e>>6)] = (ushort)bf16rne(col_w2[e]);
        ushort* c3t = (ushort*)(smem + C3_OFF);
        for (int e = t; e < 192; e += 256) c3t[(e%3)*72 + (e/3)] = (ushort)bf16rne(col_w3[e]);
        if (t < 64) {
            *(float*)(smem + DB1_OFF + t*4) = dens_b1[t];
            *(float*)(smem + DB2_OFF + t*4) = dens_b2[t];
            *(float*)(smem + CB1_OFF + t*4) = col_b1[t];
            *(float*)(smem + CB2_OFF + t*4) = col_b2[t];
        }
        if (t < 16) *(float*)(smem + DB3_OFF + t*4) = dens_b3[t];
        if (t < 4)  *(float*)(smem + CB3_OFF + t*4) = (t < 3) ? col_b3[t] : 0.f;
    }
    __syncthreads();

    const int w = t >> 6, lane = t & 63, l15 = lane & 15, q = lane >> 4;
    const int q16 = q * 16;
    char* wact = smem + ACT_OFF + w*9216;

    // ---- preload persistent A-frags for the three 64x64 layers (96 VGPRs) ----
    short8 aD2[8], aC1[8], aC2[8];
#pragma unroll
    for (int mt = 0; mt < 4; ++mt)
#pragma unroll
        for (int kk = 0; kk < 2; ++kk) {
            const int ro = (mt*16 + l15)*144 + kk*64 + q16;
            aD2[mt*2+kk] = *(const short8*)(smem + W2_OFF + ro);
            aC1[mt*2+kk] = *(const short8*)(smem + C1_OFF + ro);
            aC2[mt*2+kk] = *(const short8*)(smem + C2_OFF + ro);
        }
    __syncthreads();   // staging area now reusable as act buffers

    const float a0x = aabb[0], a0y = aabb[1], a0z = aabb[2];
    const float ivx = 1.f/(aabb[3]-a0x), ivy = 1.f/(aabb[4]-a0y), ivz = 1.f/(aabb[5]-a0z);

    const int ntiles = (n + 255) >> 8;
    const int stride = gridDim.x;

    // ---- pipeline prologue: stage inputs for first tile ----
    uint encp_s[16], ep_s[8];
    int cam_s;
    {
        const int sc0 = min(blockIdx.x*256 + w*64 + lane, n - 1);
        const float rx = ray[3*sc0], ry = ray[3*sc0+1], rz = ray[3*sc0+2];
        const float dx = dirs[3*sc0], dy = dirs[3*sc0+1], dz = dirs[3*sc0+2];
        cam_s = cam_idx[sc0];
        stage_inputs(rx, ry, rz, dx, dy, dz, a0x, a0y, a0z, ivx, ivy, ivz,
                     ht, dir_w1, dir_b1, dir_w2, dir_b2, enc, encp_s, ep_s);
    }

    for (int tile = blockIdx.x; tile < ntiles; tile += stride) {
        const int base = tile*256 + w*64;
        if (base >= n) continue;               // wave-uniform; later tiles also OOB
        const bool full = (base + 64 <= n);    // wave-uniform
        float* otile = out + (size_t)base * 19;

        // ---- A: write staged enc -> act feats 0..31 ----
        uint4* arow = (uint4*)(wact + lane*144);
        arow[0] = make_uint4(encp_s[0],  encp_s[1],  encp_s[2],  encp_s[3]);
        arow[1] = make_uint4(encp_s[4],  encp_s[5],  encp_s[6],  encp_s[7]);
        arow[2] = make_uint4(encp_s[8],  encp_s[9],  encp_s[10], encp_s[11]);
        arow[3] = make_uint4(encp_s[12], encp_s[13], encp_s[14], encp_s[15]);

        // ---- B: issue next tile's input loads (latency hidden by chain) ----
        const int scn = min((tile + stride)*256 + w*64 + lane, n - 1);
        const float rxn = ray[3*scn], ryn = ray[3*scn+1], rzn = ray[3*scn+2];
        const float dxn = dirs[3*scn], dyn = dirs[3*scn+1], dzn = dirs[3*scn+2];
        const int camn = cam_idx[scn];

        // ---- C: dens chain ----
        {   // dens1: 32 -> 64, relu (K=32), bias as C-init
            short8 a1[4];
            f32x4 bf[4];
#pragma unroll
            for (int mt = 0; mt < 4; ++mt) {
                a1[mt] = *(const short8*)(smem + W1_OFF + (mt*16 + l15)*80 + q16);
                bf[mt] = *(const f32x4*)(smem + DB1_OFF + mt*64 + q16);
            }
#pragma unroll
            for (int nt = 0; nt < 4; ++nt) {
                char* rowp = wact + (nt*16 + l15)*144;
                short8 b = *(const short8*)(rowp + q16);
                f32x4 acc[4];
#pragma unroll
                for (int mt = 0; mt < 4; ++mt)
                    acc[mt] = MFMA(a1[mt], b, bf[mt]);
                layer_wb(acc, rowp, q);
            }
        }
        layer64(wact, aD2, smem + DB2_OFF, l15, q);   // dens2
        {   // dens3: 64 -> 16 ; density+geo out, geo -> cin slots 49..63
            short8 a0 = *(const short8*)(smem + W3_OFF + l15*144 + q16);
            short8 a1 = *(const short8*)(smem + W3_OFF + l15*144 + 64 + q16);
            f32x4 bb3 = *(const f32x4*)(smem + DB3_OFF + q16);
#pragma unroll
            for (int nt = 0; nt < 4; ++nt) {
                char* rowp = wact + (nt*16 + l15)*144;
                short8 b0 = *(const short8*)(rowp + q16);
                short8 b1 = *(const short8*)(rowp + 64 + q16);
                f32x4 z = MFMA(a0, b0, bb3);
                f32x4 v = MFMA(a1, b1, z);
                uint2 g;
                g.x = pktr(q == 0 ? 0.f : v[0], v[1]);
                g.y = pktr(v[2], v[3]);
                *(uint2*)(rowp + 96 + 8*q) = g;
                if (q == 0) v[0] = fmaxf(v[0], 0.f);   // density relu
                const int sg = nt*16 + l15;
                if (full || base + sg < n)
                    *(f32x4a*)(otile + sg*19 + 3 + 4*q) = v;
            }
        }

        // ---- D: app gather (staged cam) + staged edir -> cin ----
        {
            const float4* ap = (const float4*)(app_emb + (size_t)cam_s * 32);
            uint pk[16];
#pragma unroll
            for (int qd = 0; qd < 8; ++qd) {
                const float4 vv = ap[qd];
                pk[2*qd]   = pktr(vv.x, vv.y);
                pk[2*qd+1] = pktr(vv.z, vv.w);
            }
            arow[0] = make_uint4(pk[0],  pk[1],  pk[2],  pk[3]);   // app 0..31
            arow[1] = make_uint4(pk[4],  pk[5],  pk[6],  pk[7]);
            arow[2] = make_uint4(pk[8],  pk[9],  pk[10], pk[11]);
            arow[3] = make_uint4(pk[12], pk[13], pk[14], pk[15]);
            arow[4] = make_uint4(ep_s[0], ep_s[1], ep_s[2], ep_s[3]); // edir 32..47
            arow[5] = make_uint4(ep_s[4], ep_s[5], ep_s[6], ep_s[7]);
        }

        // ---- E: col chain ----
        layer64(wact, aC1, smem + CB1_OFF, l15, q);   // col1
        layer64(wact, aC2, smem + CB2_OFF, l15, q);   // col2
        {   // col3: 64 -> 3 (rows 0..2), sigmoid
            short8 a0 = *(const short8*)(smem + C3_OFF + l15*144 + q16);
            short8 a1 = *(const short8*)(smem + C3_OFF + l15*144 + 64 + q16);
            f32x4 bbc = *(const f32x4*)(smem + CB3_OFF);
#pragma unroll
            for (int nt = 0; nt < 4; ++nt) {
                char* rowp = wact + (nt*16 + l15)*144;
                short8 b0 = *(const short8*)(rowp + q16);
                short8 b1 = *(const short8*)(rowp + 64 + q16);
                f32x4 z = MFMA(a0, b0, bbc);
                f32x4 v = MFMA(a1, b1, z);
                const int sg = nt*16 + l15;
                if (q == 0 && (full || base + sg < n)) {
                    float* op = otile + sg*19;
                    f32x2a r01;
                    r01[0] = 1.f / (1.f + __expf(-v[0]));
                    r01[1] = 1.f / (1.f + __expf(-v[1]));
                    *(f32x2a*)op = r01;
                    op[2] = 1.f / (1.f + __expf(-v[2]));
                }
            }
        }

        // ---- F: compute next tile's enc/dir into staged regs ----
        cam_s = camn;
        stage_inputs(rxn, ryn, rzn, dxn, dyn, dzn, a0x, a0y, a0z,
                     ivx, ivy, ivz, ht, dir_w1, dir_b1, dir_w2, dir_b2,
                     enc, encp_s, ep_s);
    }
}

extern "C" void kernel_launch(void* const* d_in, const int* in_sizes, int n_in,
                              void* d_out, int out_size, void* d_ws, size_t ws_size,
                              hipStream_t stream)
{
    const float* ray  = (const float*)d_in[0];
    const float* dirs = (const float*)d_in[1];
    const int*   cam  = (const int*)  d_in[2];
    const float* aabb = (const float*)d_in[3];
    const float* ht   = (const float*)d_in[4];
    const float* dw1  = (const float*)d_in[5];
    const float* db1  = (const float*)d_in[6];
    const float* dw2  = (const float*)d_in[7];
    const float* db2  = (const float*)d_in[8];
    const float* nw1  = (const float*)d_in[9];
    const float* nb1  = (const float*)d_in[10];
    const float* nw2  = (const float*)d_in[11];
    const float* nb2  = (const float*)d_in[12];
    const float* nw3  = (const float*)d_in[13];
    const float* nb3  = (const float*)d_in[14];
    const float* cw1  = (const float*)d_in[15];
    const float* cb1  = (const float*)d_in[16];
    const float* cw2  = (const float*)d_in[17];
    const float* cb2  = (const float*)d_in[18];
    const float* cw3  = (const float*)d_in[19];
    const float* cb3  = (const float*)d_in[20];
    const float* app  = (const float*)d_in[21];
    float* out = (float*)d_out;

    const int n = in_sizes[0] / 3;

    // Reproduce Python's RES (same libm): GROWTH = exp((ln2048-ln16)/15)
    EncC enc;
    const double growth = exp((log(2048.0) - log(16.0)) / 15.0);
    for (int i = 0; i < 16; ++i) {
        const int r = (int)(16.0 * pow(growth, (double)i));
        enc.rf[i] = (float)(r - 1);
    }

    const int ntiles = (n + 255) / 256;
    const int grid = ntiles < 768 ? ntiles : 768;
    nerf_mfma<<<grid, 256, 0, stream>>>(
        ray, dirs, cam, aabb, ht,
        dw1, db1, dw2, db2,
        nw1, nb1, nw2, nb2, nw3, nb3,
        cw1, cb1, cw2, cb2, cw3, cb3,
        app, out, n, enc);
}